// Round 7
// baseline (75.088 us; speedup 1.0000x reference)
//
#include <hip/hip_runtime.h>

#define NB 4096               // 12-bit bins: sign+exp+3 mantissa bits
#define FB_BLOCKS 512
#define FB_THREADS 1024
#define SCALE 32768.0f        // 15-bit fixed point for p, t, p*t
typedef unsigned long long u64;

// Monotone float -> uint map (ascending). Larger curvature -> larger key.
__device__ __forceinline__ unsigned sortable_key(float f) {
  unsigned u = __float_as_uint(f);
  return u ^ ((u & 0x80000000u) ? 0xFFFFFFFFu : 0x80000000u);
}

// Per-element: 2 packed u64 LDS atomics.
//   hA[bin] += (1<<32) | t_q        (count in high, sum_t in low)
//   hB[bin] += (p_q<<32) | pt_q     (sum_p in high, sum_pt in low)
// Low-word sums <= 32768*32768 = 2^30 -> never carry into high field.
__device__ __forceinline__ void accum4(u64* __restrict__ hA,
                                       u64* __restrict__ hB,
                                       float4 cv, float4 xv, float4 tv) {
#pragma unroll
  for (int j = 0; j < 4; ++j) {
    float cj = (&cv.x)[j], xj = (&xv.x)[j], tj = (&tv.x)[j];
    unsigned bin = sortable_key(cj) >> 20;
    float p = __fdividef(1.f, 1.f + __expf(-xj));
    unsigned up  = __float2uint_rn(p * SCALE);
    unsigned ut  = __float2uint_rn(tj * SCALE);
    unsigned upt = __float2uint_rn(p * tj * SCALE);
    atomicAdd(&hA[bin], (((u64)1) << 32) | (u64)ut);    // ds_add_u64
    atomicAdd(&hB[bin], (((u64)up) << 32) | (u64)upt);  // ds_add_u64
  }
}

// Single pass over all three arrays with 1-deep load prefetch.
// Global bins: g[0..NB)=count, [NB..2NB)=sum_p, [2NB..3NB)=sum_t,
// [3NB..4NB)=sum_pt (all u64).
__global__ void __launch_bounds__(FB_THREADS, 2) fused_kernel(
    const float* __restrict__ xin, const float* __restrict__ tin,
    const float* __restrict__ cin, u64* __restrict__ g,
    int nvec, int ntail) {
  __shared__ u64 hA[NB];  // 32 KB
  __shared__ u64 hB[NB];  // 32 KB
  for (int i = threadIdx.x; i < NB; i += FB_THREADS) { hA[i] = 0; hB[i] = 0; }
  __syncthreads();

  const float4* __restrict__ x4 = (const float4*)xin;
  const float4* __restrict__ t4 = (const float4*)tin;
  const float4* __restrict__ c4 = (const float4*)cin;

  int idx = blockIdx.x * FB_THREADS + threadIdx.x;
  int stride = gridDim.x * FB_THREADS;

  // software pipeline: prefetch next iteration's 3 float4s before
  // processing the current ones.
  int i = idx;
  bool valid = (i < nvec);
  float4 cc, xx, tt;
  if (valid) { cc = c4[i]; xx = x4[i]; tt = t4[i]; }
  while (valid) {
    int inext = i + stride;
    bool vnext = (inext < nvec);
    float4 cn, xn, tn;
    if (vnext) { cn = c4[inext]; xn = x4[inext]; tn = t4[inext]; }
    accum4(hA, hB, cc, xx, tt);   // overlaps with the loads above
    cc = cn; xx = xn; tt = tn;
    i = inext;
    valid = vnext;
  }
  if (idx == 0) {  // scalar tail (N % 4) -> global bins directly
    for (int e = nvec * 4; e < nvec * 4 + ntail; ++e) {
      float cj = cin[e], xj = xin[e], tj = tin[e];
      unsigned bin = sortable_key(cj) >> 20;
      float p = __fdividef(1.f, 1.f + __expf(-xj));
      atomicAdd(&g[bin], (u64)1);
      atomicAdd(&g[NB + bin], (u64)__float2uint_rn(p * SCALE));
      atomicAdd(&g[2 * NB + bin], (u64)__float2uint_rn(tj * SCALE));
      atomicAdd(&g[3 * NB + bin], (u64)__float2uint_rn(p * tj * SCALE));
    }
  }
  __syncthreads();

  // merge nonzero bins, unpacked (packed sums would overflow across blocks)
  for (int b = threadIdx.x; b < NB; b += FB_THREADS) {
    u64 A = hA[b];
    if (A) {
      u64 B = hB[b];
      atomicAdd(&g[b], A >> 32);                  // count
      atomicAdd(&g[NB + b], B >> 32);             // sum_p
      atomicAdd(&g[2 * NB + b], A & 0xFFFFFFFFu); // sum_t
      atomicAdd(&g[3 * NB + b], B & 0xFFFFFFFFu); // sum_pt
    }
  }
}

// One block, 1024 threads x 4 bins: suffix-scan counts from the top to find
// the K crossing, then weighted f64 reduction of bin aggregates + dice.
__global__ void __launch_bounds__(1024) final_kernel(
    const u64* __restrict__ g, unsigned K, float* __restrict__ out) {
  __shared__ unsigned waveTot[16];
  __shared__ unsigned waveSuf[16];
  __shared__ unsigned s_bsel;
  __shared__ double s_frac;
  __shared__ double dsum[3][16];

  int tid = threadIdx.x;
  int lane = tid & 63;
  int wid = tid >> 6;

  unsigned base = (unsigned)tid * 4u;
  unsigned c[4];
  unsigned cs = 0;
#pragma unroll
  for (int j = 0; j < 4; ++j) { c[j] = (unsigned)g[base + j]; cs += c[j]; }

  unsigned incl = cs;
#pragma unroll
  for (int off = 1; off < 64; off <<= 1) {
    unsigned o = __shfl_down(incl, off);
    if (lane + off < 64) incl += o;
  }
  if (lane == 0) waveTot[wid] = incl;
  __syncthreads();
  if (tid == 0) {
    unsigned run = 0;
    for (int w = 15; w >= 0; --w) { waveSuf[w] = run; run += waveTot[w]; }
  }
  __syncthreads();

  unsigned run = waveSuf[wid] + (incl - cs);  // count strictly above my chunk
#pragma unroll
  for (int j = 3; j >= 0; --j) {  // high -> low
    unsigned cc = c[j];
    if (cc && run < K && run + cc >= K) {  // unique crossing
      s_bsel = base + (unsigned)j;
      s_frac = (double)(K - run) / (double)cc;
    }
    run += cc;
  }
  __syncthreads();

  unsigned bsel = s_bsel;
  double frac = s_frac;

  double sp = 0, st = 0, spt = 0;
#pragma unroll
  for (int j = 0; j < 4; ++j) {
    unsigned b = base + j;
    double w = (b > bsel) ? 1.0 : ((b == bsel) ? frac : 0.0);
    if (w != 0.0) {
      sp  += w * (double)g[NB + b];
      st  += w * (double)g[2 * NB + b];
      spt += w * (double)g[3 * NB + b];
    }
  }
#pragma unroll
  for (int off = 32; off > 0; off >>= 1) {
    sp  += __shfl_down(sp, off);
    st  += __shfl_down(st, off);
    spt += __shfl_down(spt, off);
  }
  if (lane == 0) { dsum[0][wid] = sp; dsum[1][wid] = st; dsum[2][wid] = spt; }
  __syncthreads();
  if (tid == 0) {
    double A = 0, B = 0, C = 0;
#pragma unroll
    for (int w = 0; w < 16; ++w) { A += dsum[0][w]; B += dsum[1][w]; C += dsum[2][w]; }
    const double inv = 1.0 / (double)SCALE;
    A *= inv; B *= inv; C *= inv;
    double dice = (2.0 * C + 1.0) / (A + B + 1.0);
    out[0] = (float)(1.0 - dice);
  }
}

extern "C" void kernel_launch(void* const* d_in, const int* in_sizes, int n_in,
                              void* d_out, int out_size, void* d_ws, size_t ws_size,
                              hipStream_t stream) {
  const float* d_inputs  = (const float*)d_in[0];
  const float* d_targets = (const float*)d_in[1];
  const float* d_curv    = (const float*)d_in[2];
  float* out = (float*)d_out;

  int N = in_sizes[2];
  unsigned K = (unsigned)(0.4 * (double)N);  // matches Python int(R*N)

  u64* g = (u64*)d_ws;  // 4 * NB u64 = 128 KB

  // zero global bins every call (harness doesn't re-poison d_ws)
  hipMemsetAsync(d_ws, 0, 4 * NB * sizeof(u64), stream);

  int nvec = N / 4;
  int ntail = N - nvec * 4;

  fused_kernel<<<FB_BLOCKS, FB_THREADS, 0, stream>>>(d_inputs, d_targets,
                                                     d_curv, g, nvec, ntail);
  final_kernel<<<1, 1024, 0, stream>>>(g, K, out);
}